// Round 1
// 254.774 us; speedup vs baseline: 1.2320x; 1.2320x over previous
//
#include <hip/hip_runtime.h>

typedef __attribute__((ext_vector_type(8))) short bf16x8;
typedef __attribute__((ext_vector_type(4))) float f32x4;
typedef __attribute__((ext_vector_type(4))) _Float16 f16x4;

static __device__ __forceinline__ unsigned short f32_to_bf16(float f) {
    unsigned int x = __float_as_uint(f);
    x += 0x7fffu + ((x >> 16) & 1u);   // round-to-nearest-even
    return (unsigned short)(x >> 16);
}

static constexpr int SMEM_BYTES = 38400;

// Cost volume as banded GEMM: out[n,j,h,x] = l̂[:,x]·r̂[:,x-j] = (l·r)·invl·invr.
// v2: raw-bf16 staging (scale AFTER mfma), one column per thread, f16 swizzled
// obuf, uniform 256-thread/TX=64 blocks, single fused launch.
template<int C, int H, int W, int D, int TX, int NT>
__device__ __forceinline__
void cv_body(const int bx, const float* __restrict__ Lp, const float* __restrict__ Rp,
             float* __restrict__ out, char* smem)
{
    constexpr int RS = TX + D;        // staged y range: [X0-D, X0+TX)
    constexpr int AS = C + 8;         // bf16 row stride (odd*4-word stride: conflict-free b128)
    constexpr int KC = C / 32;        // mfma k-steps
    constexpr int NW = NT / 64;       // waves per block = x-strips per block
    static_assert(NW == TX / 16, "one wave per 16-wide x-strip");
    static_assert(TX + RS <= NT, "staging: one column per thread");
    static_assert(TX == 64, "obuf swizzle assumes 128B rows; wave-aligned branch split");
    static_assert(RS * AS * 2 + TX * AS * 2 + (RS + TX) * 4 + D * TX * 2 <= SMEM_BYTES, "lds");

    unsigned short* Abf = (unsigned short*)smem;          // [RS][AS] raw r, bf16
    unsigned short* Bbf = Abf + RS * AS;                  // [TX][AS] raw l, bf16
    float* invA = (float*)(Bbf + TX * AS);                // [RS] 1/|r|
    float* invB = invA + RS;                              // [TX] 1/|l|
    char*  obuf = (char*)(invB + TX);                     // [D][TX] f16, XOR-swizzled

    const int tid = threadIdx.x;
    constexpr int NXB = W / TX;
    const int xb = bx % NXB;
    const int h  = (bx / NXB) % H;
    const int n  = bx / (NXB * H);
    const int X0 = xb * TX;

    const size_t CH = (size_t)H * W;
    const float* Lb = Lp + ((size_t)n * C * H + h) * W;
    const float* Rb = Rp + ((size_t)n * C * H + h) * W;

    // ---- stage: one spatial column per thread. Coalesced dword loads (lanes =
    //      consecutive columns), convert raw->bf16, accumulate ssq in fp32. ----
    const int col = tid;
    if (col < TX + RS) {
        const float* src; unsigned short* dst; int g; bool zero;
        if (col < TX) { g = X0 + col;            src = Lb; dst = Bbf + col * AS;        zero = false; }
        else          { g = X0 - D + (col - TX); src = Rb; dst = Abf + (col - TX) * AS; zero = g < 0; }
        float ssq = 0.f;
        if (!zero) {
            #pragma unroll
            for (int c0 = 0; c0 < C; c0 += 8) {
                float v[8];
                #pragma unroll
                for (int k = 0; k < 8; ++k) v[k] = src[(size_t)(c0 + k) * CH + g];
                union { unsigned short us[8]; uint4 q; } p;
                #pragma unroll
                for (int k = 0; k < 8; ++k) { ssq += v[k] * v[k]; p.us[k] = f32_to_bf16(v[k]); }
                *(uint4*)&dst[c0] = p.q;      // b128, conflict-free (AS pad)
            }
        } else {
            const uint4 z = {0u, 0u, 0u, 0u};
            #pragma unroll
            for (int c0 = 0; c0 < C; c0 += 8) *(uint4*)&dst[c0] = z;
        }
        const float inv = 1.0f / fmaxf(sqrtf(ssq), 1e-12f);
        if (col < TX) invB[col] = inv; else invA[col - TX] = inv;
    }
    __syncthreads();

    // ---- banded MFMA sweep: wave w owns x-strip [16w, 16w+16) ----
    const int wave = tid >> 6, lane = tid & 63;
    const int colc = lane & 15, quad = lane >> 4;

    bf16x8 bfr[KC];
    #pragma unroll
    for (int kc = 0; kc < KC; ++kc)
        bfr[kc] = *(const bf16x8*)&Bbf[(wave * 16 + colc) * AS + kc * 32 + quad * 8];

    const int xl = wave * 16 + colc;
    const float sB = invB[xl];

    #pragma unroll
    for (int t = 0; t <= D / 16; ++t) {
        const int yt = wave + t;                  // exact band cover
        f32x4 acc = {0.f, 0.f, 0.f, 0.f};
        #pragma unroll
        for (int kc = 0; kc < KC; ++kc) {
            const bf16x8 a = *(const bf16x8*)&Abf[(yt * 16 + colc) * AS + kc * 32 + quad * 8];
            acc = __builtin_amdgcn_mfma_f32_16x16x32_bf16(a, bfr[kc], acc, 0, 0, 0);
        }
        // D layout: col=lane&15 (x), row=quad*4+r (y); j = x - y (+D offset)
        const int yb = yt * 16 + quad * 4;
        const int jb = D + xl - yb;
        #pragma unroll
        for (int r = 0; r < 4; ++r) {
            const int j = jb - r;
            if (j >= 0 && j < D) {
                const float val = acc[r] * sB * invA[yb + r];   // scale after mfma
                *(_Float16*)(obuf + (((j * TX + xl) * 2) ^ ((j & 7) << 4))) = (_Float16)val;
            }
        }
    }
    __syncthreads();

    // ---- coalesced writeout: lane -> (j = idx/16, 4 consecutive x) ----
    constexpr int NIT = D * TX / 4 / NT;
    float* orow = out + ((size_t)n * D) * CH + (size_t)h * W + X0;
    #pragma unroll
    for (int it = 0; it < NIT; ++it) {
        const int idx = it * NT + tid;
        const int j = idx >> 4, xo = idx & 15;
        const f16x4 hv = *(const f16x4*)(obuf + (((j * TX + xo * 4) * 2) ^ ((j & 7) << 4)));
        float4 o;
        o.x = (float)hv.x; o.y = (float)hv.y; o.z = (float)hv.z; o.w = (float)hv.w;
        *(float4*)&orow[(size_t)j * CH + xo * 4] = o;
    }
}

constexpr int G0 = 2 * 256 * (512 / 64);   // 4096
constexpr int G1 = 2 * 128 * (256 / 64);   // 1024
constexpr int G2 = 2 * 64  * (128 / 64);   // 256

static __device__ __forceinline__ int xcd_swz(int b, int nwg) {
    // bijective (nwg % 8 == 0): consecutive logical tiles land on one XCD's L2
    return (b & 7) * (nwg >> 3) + (b >> 3);
}

__global__ __launch_bounds__(256, 4)
void fused_cv(const float* __restrict__ l0, const float* __restrict__ r0, float* __restrict__ o0,
              const float* __restrict__ l1, const float* __restrict__ r1, float* __restrict__ o1,
              const float* __restrict__ l2, const float* __restrict__ r2, float* __restrict__ o2)
{
    __shared__ __align__(16) char smem[SMEM_BYTES];
    const int bid = blockIdx.x;
    if (bid < G0)
        cv_body<32, 256, 512, 128, 64, 256>(xcd_swz(bid, G0), l0, r0, o0, smem);
    else if (bid < G0 + G1)
        cv_body<64, 128, 256,  64, 64, 256>(xcd_swz(bid - G0, G1), l1, r1, o1, smem);
    else
        cv_body<96,  64, 128,  32, 64, 256>(xcd_swz(bid - G0 - G1, G2), l2, r2, o2, smem);
}

extern "C" void kernel_launch(void* const* d_in, const int* in_sizes, int n_in,
                              void* d_out, int out_size, void* d_ws, size_t ws_size,
                              hipStream_t stream) {
    (void)in_sizes; (void)n_in; (void)d_ws; (void)ws_size; (void)out_size;
    const float* l0 = (const float*)d_in[0];
    const float* r0 = (const float*)d_in[1];
    const float* l1 = (const float*)d_in[2];
    const float* r1 = (const float*)d_in[3];
    const float* l2 = (const float*)d_in[4];
    const float* r2 = (const float*)d_in[5];

    float* o0 = (float*)d_out;
    float* o1 = o0 + (size_t)2 * 128 * 256 * 512;
    float* o2 = o1 + (size_t)2 * 64 * 128 * 256;

    // Single fused launch: 5376 blocks x 256 thr, 38.4 KB LDS -> 4 blocks/CU,
    // L1/L2 blocks backfill L0's drain tail.
    fused_cv<<<G0 + G1 + G2, 256, 0, stream>>>(l0, r0, o0, l1, r1, o1, l2, r2, o2);
}